// Round 1
// 250.665 us; speedup vs baseline: 1.0508x; 1.0508x over previous
//
#include <hip/hip_runtime.h>

// Multi-threshold LIF accumulation.
// x: [T=4, B, N, C] fp32; thresholds: [4] fp32; out: [T, B, N, C] fp32.
// Each thread owns 4 consecutive channel elements (one float4) of one
// spatial position, loads all T=4 timestep values, runs the 4-threshold x
// 4-timestep LIF recurrence entirely in registers, writes 4 float4 outputs.
// Pure HBM-bandwidth kernel: 154 MB read + 154 MB write, zero reuse.
//
// This revision: non-temporal (evict-first) load/store policy on the
// streaming data — it is read-once/write-once and only pollutes L2/LLC
// (which the harness poison fill has already thrashed) — plus pinned
// 8 waves/SIMD occupancy via __launch_bounds__(256, 8).

static constexpr int TT = 4;  // timesteps
static constexpr int JJ = 4;  // threshold blocks

// Native clang ext-vector so __builtin_nontemporal_{load,store} accepts it.
typedef float f32x4 __attribute__((ext_vector_type(4)));

__global__ __launch_bounds__(256, 8) void lif_multithresh_kernel(
    const f32x4* __restrict__ x,
    const float* __restrict__ th,
    f32x4* __restrict__ out,
    int n4)  // float4s per timestep slab
{
    const int i = blockIdx.x * blockDim.x + threadIdx.x;
    if (i >= n4) return;

    // Thresholds are wave-uniform -> scalar loads, issued alongside the
    // vector loads below.
    float thr[JJ];
#pragma unroll
    for (int j = 0; j < JJ; ++j) thr[j] = th[j];

    // Load all timesteps for this position (coalesced 16B non-temporal loads).
    f32x4 xv[TT];
#pragma unroll
    for (int t = 0; t < TT; ++t)
        xv[t] = __builtin_nontemporal_load(&x[(size_t)t * (size_t)n4 + (size_t)i]);

    f32x4 acc[TT];
#pragma unroll
    for (int t = 0; t < TT; ++t)
        acc[t] = (f32x4)0.0f;

    // LIF: v = v + (x - v)/tau (tau = 2, exact *0.5), spike = (v >= th),
    // hard reset v = 0 on spike. Op order matches the reference exactly
    // (do NOT refactor to (v+x)*0.5 — different rounding, spike flips).
#pragma unroll
    for (int j = 0; j < JJ; ++j) {
        const float tj = thr[j];
#pragma unroll
        for (int c = 0; c < 4; ++c) {
            float v = 0.0f;
#pragma unroll
            for (int t = 0; t < TT; ++t) {
                v = v + (xv[t][c] - v) * 0.5f;
                const bool s = (v >= tj);
                acc[t][c] += s ? 1.0f : 0.0f;
                v = s ? 0.0f : v;
            }
        }
    }

#pragma unroll
    for (int t = 0; t < TT; ++t)
        __builtin_nontemporal_store(acc[t], &out[(size_t)t * (size_t)n4 + (size_t)i]);
}

extern "C" void kernel_launch(void* const* d_in, const int* in_sizes, int n_in,
                              void* d_out, int out_size, void* d_ws, size_t ws_size,
                              hipStream_t stream) {
    const float* x  = (const float*)d_in[0];
    const float* th = (const float*)d_in[1];
    float* out = (float*)d_out;

    const int total = in_sizes[0];       // T*B*N*C
    const int S = total / TT;            // B*N*C per timestep
    const int n4 = S / 4;                // float4s per timestep (S % 4 == 0)

    const int block = 256;
    const int grid = (n4 + block - 1) / block;
    lif_multithresh_kernel<<<grid, block, 0, stream>>>(
        (const f32x4*)x, th, (f32x4*)out, n4);
}

// Round 2
// 250.642 us; speedup vs baseline: 1.0509x; 1.0001x over previous
//
#include <hip/hip_runtime.h>

// Multi-threshold LIF accumulation.
// x: [T=4, B, N, C] fp32; thresholds: [4] fp32; out: [T, B, N, C] fp32.
// Pure HBM-bandwidth kernel: 154 MB read + 154 MB write, zero reuse.
//
// Revision history:
//   r0: float4-per-thread, registers-only recurrence           -> 263 µs
//   r1: + non-temporal loads/stores (evict-first, no RFO)      -> 251 µs
//   r2 (this): 2x float4 per thread (lane-contiguous pairs) so each wave
//       moves 2 KB per stream per visit (8 NT loads in flight), halving
//       block churn. launch_bounds relaxed to (256,4) for ~84 VGPR.

static constexpr int TT = 4;  // timesteps
static constexpr int JJ = 4;  // threshold blocks
static constexpr int UU = 2;  // float4 groups per thread

// Native clang ext-vector so __builtin_nontemporal_{load,store} accepts it.
typedef float f32x4 __attribute__((ext_vector_type(4)));

__global__ __launch_bounds__(256, 4) void lif_multithresh_kernel(
    const f32x4* __restrict__ x,
    const float* __restrict__ th,
    f32x4* __restrict__ out,
    int n4)  // float4s per timestep slab
{
    const int tid = threadIdx.x;
    // Thread owns float4 indices i0 and i0+256 (both coalesced across lanes).
    const int i0 = blockIdx.x * (256 * UU) + tid;
    const int i1 = i0 + 256;
    if (i0 >= n4) return;
    const bool has2 = (i1 < n4);

    // Thresholds are wave-uniform -> scalar loads.
    float thr[JJ];
#pragma unroll
    for (int j = 0; j < JJ; ++j) thr[j] = th[j];

    // Load all timesteps for both positions (coalesced 16B NT loads, 8 in flight).
    f32x4 xv[UU][TT];
#pragma unroll
    for (int t = 0; t < TT; ++t) {
        xv[0][t] = __builtin_nontemporal_load(&x[(size_t)t * (size_t)n4 + (size_t)i0]);
        if (has2)
            xv[1][t] = __builtin_nontemporal_load(&x[(size_t)t * (size_t)n4 + (size_t)i1]);
    }

    f32x4 acc[UU][TT];
#pragma unroll
    for (int u = 0; u < UU; ++u)
#pragma unroll
        for (int t = 0; t < TT; ++t) acc[u][t] = (f32x4)0.0f;

    // LIF: v = v + (x - v)/tau (tau = 2, exact *0.5), spike = (v >= th),
    // hard reset v = 0 on spike. Op order matches the reference exactly
    // (do NOT refactor to (v+x)*0.5 — different rounding, spike flips).
#pragma unroll
    for (int u = 0; u < UU; ++u) {
#pragma unroll
        for (int j = 0; j < JJ; ++j) {
            const float tj = thr[j];
#pragma unroll
            for (int c = 0; c < 4; ++c) {
                float v = 0.0f;
#pragma unroll
                for (int t = 0; t < TT; ++t) {
                    v = v + (xv[u][t][c] - v) * 0.5f;
                    const bool s = (v >= tj);
                    acc[u][t][c] += s ? 1.0f : 0.0f;
                    v = s ? 0.0f : v;
                }
            }
        }
    }

#pragma unroll
    for (int t = 0; t < TT; ++t) {
        __builtin_nontemporal_store(acc[0][t], &out[(size_t)t * (size_t)n4 + (size_t)i0]);
        if (has2)
            __builtin_nontemporal_store(acc[1][t], &out[(size_t)t * (size_t)n4 + (size_t)i1]);
    }
}

extern "C" void kernel_launch(void* const* d_in, const int* in_sizes, int n_in,
                              void* d_out, int out_size, void* d_ws, size_t ws_size,
                              hipStream_t stream) {
    const float* x  = (const float*)d_in[0];
    const float* th = (const float*)d_in[1];
    float* out = (float*)d_out;

    const int total = in_sizes[0];       // T*B*N*C
    const int S = total / TT;            // B*N*C per timestep
    const int n4 = S / 4;                // float4s per timestep (S % 4 == 0)

    const int block = 256;
    const int per_block = block * UU;    // 512 float4s per block
    const int grid = (n4 + per_block - 1) / per_block;
    lif_multithresh_kernel<<<grid, block, 0, stream>>>(
        (const f32x4*)x, th, (f32x4*)out, n4);
}